// Round 5
// baseline (482.529 us; speedup 1.0000x reference)
//
#include <hip/hip_runtime.h>
#include <stdint.h>

// Problem constants
#define B_  64
#define C_  3
#define H_  512
#define W_  512
#define OC_ 16
#define OH_ 510
#define OW_ 510

// Tile geometry: 256-thread block computes a 64(x) x 16(y) output tile,
// FOUR output pixels per thread (stacked in y) to amortize the weight
// stream / staging / epilogue overhead 4x over the invariant FMA work.
#define TX_ 64
#define TY_ 16
#define TILES_X_ 8    // ceil(510/64)
#define TILES_Y_ 32   // ceil(510/16)
#define SMW_ 66       // TX+2
#define SMH_ 18       // TY+2

// NaN-safe tanh: 1 - 2/(e^{2x}+1). For 2x overflow e=inf -> 1-0 = 1 (no inf/inf).
__device__ __forceinline__ float fast_tanh(float v) {
    float e = __expf(2.0f * v);
    return 1.0f - 2.0f * __builtin_amdgcn_rcpf(e + 1.0f);
}

__global__ __launch_bounds__(256, 4)
void conv3x3_min_tanh(const float* __restrict__ x, const float* __restrict__ wgt,
                      const float* __restrict__ bias, float* __restrict__ out) {
    __shared__ float smem[C_ * SMH_ * SMW_];   // 3*18*66*4 = 14.3 KB

    const int blk = blockIdx.x;
    const int bx = blk % TILES_X_;
    const int by = (blk / TILES_X_) % TILES_Y_;
    const int b  = blk / (TILES_X_ * TILES_Y_);
    const int ox0 = bx * TX_;
    const int oy0 = by * TY_;

    // ---- stage input tile (border-clamped; clamped values never stored) ----
    const float* xb = x + (size_t)b * C_ * H_ * W_;
    constexpr int NSTAGE = C_ * SMH_ * SMW_;   // 3564
    for (int i = threadIdx.x; i < NSTAGE; i += 256) {
        int c  = i / (SMH_ * SMW_);
        int r  = (i % (SMH_ * SMW_)) / SMW_;
        int xx = i % SMW_;
        int gy = min(oy0 + r,  H_ - 1);
        int gx = min(ox0 + xx, W_ - 1);
        smem[i] = xb[(c * H_ + gy) * W_ + gx];
    }
    __syncthreads();

    // ---- compute: thread -> outputs (ox0+lx, oy0 + tyg*4 + p), p=0..3 ----
    const int lx  = threadIdx.x & 63;
    const int tyg = threadIdx.x >> 6;   // 0..3

    // All 54 taps (3 ch x 6 rows x 3 cols) born as opaque asm outputs:
    // single-shot LDS reads, not rematerializable.
    const uint32_t lds_base = (uint32_t)(uintptr_t)(&smem[0]);
    float tap[C_][6][3];
    #pragma unroll
    for (int c = 0; c < C_; ++c)
        #pragma unroll
        for (int dy = 0; dy < 6; ++dy)
            #pragma unroll
            for (int dx = 0; dx < 3; ++dx) {
                uint32_t addr = lds_base +
                    4u * (uint32_t)((c * SMH_ + tyg * 4 + dy) * SMW_ + lx + dx);
                asm volatile("ds_read_b32 %0, %1"
                             : "=v"(tap[c][dy][dx]) : "v"(addr));
            }
    asm volatile("s_waitcnt lgkmcnt(0)" ::: "memory");
    __builtin_amdgcn_sched_barrier(0);   // rule #18

    // o-pair outer, 8 independent FMA chains (2 oc x 4 pixels) for ILP.
    float mn[4] = {__builtin_inff(), __builtin_inff(),
                   __builtin_inff(), __builtin_inff()};
    #pragma unroll
    for (int o = 0; o < OC_; o += 2) {
        float a0[4], a1[4];
        float b0 = bias[o], b1 = bias[o + 1];
        #pragma unroll
        for (int p = 0; p < 4; ++p) { a0[p] = b0; a1[p] = b1; }

        #pragma unroll
        for (int c = 0; c < C_; ++c)
            #pragma unroll
            for (int ky = 0; ky < 3; ++ky)
                #pragma unroll
                for (int kx = 0; kx < 3; ++kx) {
                    // uniform weights -> s_load, SGPR operand of v_fma_f32
                    float w0 = wgt[((o * C_ + c) * 3 + ky) * 3 + kx];
                    float w1 = wgt[(((o + 1) * C_ + c) * 3 + ky) * 3 + kx];
                    #pragma unroll
                    for (int p = 0; p < 4; ++p) {
                        a0[p] = fmaf(w0, tap[c][p + ky][kx], a0[p]);
                        a1[p] = fmaf(w1, tap[c][p + ky][kx], a1[p]);
                    }
                }
        #pragma unroll
        for (int p = 0; p < 4; ++p)
            mn[p] = fminf(mn[p], fminf(a0[p], a1[p]));
    }

    // ---- epilogue: double tanh, coalesced stores ----
    #pragma unroll
    for (int p = 0; p < 4; ++p) {
        float t = fast_tanh(fast_tanh(mn[p]));
        int oy = oy0 + tyg * 4 + p;
        int ox = ox0 + lx;
        if (oy < OH_ && ox < OW_)
            out[((size_t)b * OH_ + oy) * OW_ + ox] = t;
    }
}

extern "C" void kernel_launch(void* const* d_in, const int* in_sizes, int n_in,
                              void* d_out, int out_size, void* d_ws, size_t ws_size,
                              hipStream_t stream) {
    const float* x    = (const float*)d_in[0];
    const float* wgt  = (const float*)d_in[1];
    const float* bias = (const float*)d_in[2];
    float* out = (float*)d_out;

    dim3 grid(B_ * TILES_X_ * TILES_Y_);   // 16384 blocks
    conv3x3_min_tanh<<<grid, 256, 0, stream>>>(x, wgt, bias, out);
}

// Round 6
// 120.899 us; speedup vs baseline: 3.9912x; 3.9912x over previous
//
#include <hip/hip_runtime.h>
#include <hip/hip_bf16.h>
#include <stdint.h>

// Problem constants
#define B_  64
#define C_  3
#define H_  512
#define W_  512
#define OC_ 16
#define OH_ 510
#define OW_ 510

// Tile: 256-thread block -> 64(x) x 16(y) outputs. 4 waves; wave w owns
// y-rows 4w..4w+3. Per wave: 16 MFMA "sets" (4 rows x 4 x-subtiles of 16).
#define TX_ 64
#define TY_ 16
#define TILES_X_ 8    // ceil(510/64)
#define TILES_Y_ 32   // ceil(510/16)
#define SMW_ 66       // TX+2
#define SMH_ 18       // TY+2

typedef __attribute__((ext_vector_type(8))) short bf16x8;   // MFMA A/B frag
typedef __attribute__((ext_vector_type(4))) float f32x4;    // MFMA C/D frag

// NaN-safe tanh: 1 - 2/(e^{2x}+1). e=inf -> 1 (no inf/inf NaN).
__device__ __forceinline__ float fast_tanh(float v) {
    float e = __expf(2.0f * v);
    return 1.0f - 2.0f * __builtin_amdgcn_rcpf(e + 1.0f);
}
__device__ __forceinline__ short f2bf(float f) {
    __hip_bfloat16 h = __float2bfloat16(f);   // RNE; compiler emits v_cvt_pk
    return *reinterpret_cast<short*>(&h);
}

__global__ __launch_bounds__(256, 4)
void conv3x3_min_tanh_mfma(const float* __restrict__ x,
                           const float* __restrict__ wgt,
                           const float* __restrict__ bias,
                           float* __restrict__ out) {
    __shared__ float smem[C_ * SMH_ * SMW_];   // 3*18*66*4 = 14.3 KB fp32

    const int blk = blockIdx.x;
    const int bx = blk % TILES_X_;
    const int by = (blk / TILES_X_) % TILES_Y_;
    const int b  = blk / (TILES_X_ * TILES_Y_);
    const int ox0 = bx * TX_;
    const int oy0 = by * TY_;

    // ---- stage fp32 input tile (border-clamped; clamps feed dead pixels only)
    const float* xb = x + (size_t)b * C_ * H_ * W_;
    constexpr int NSTAGE = C_ * SMH_ * SMW_;   // 3564
    for (int i = threadIdx.x; i < NSTAGE; i += 256) {
        int c   = i / (SMH_ * SMW_);
        int rem = i - c * (SMH_ * SMW_);
        int r   = rem / SMW_;
        int xx  = rem - r * SMW_;
        int gy  = min(oy0 + r,  H_ - 1);
        int gx  = min(ox0 + xx, W_ - 1);
        smem[i] = xb[(c * H_ + gy) * W_ + gx];
    }
    __syncthreads();

    const int lane = threadIdx.x & 63;
    const int wv   = threadIdx.x >> 6;   // wave id 0..3
    const int nf   = lane & 15;          // A: oc ; B: pixel-x offset
    const int g    = lane >> 4;          // k-chunk: k = 8g+e

    // ---- W-frag (A operand): A[m=oc=nf][k=8g+e] = wgt[nf*27 + k], 0-pad k>=27
    bf16x8 wf;
    #pragma unroll
    for (int e = 0; e < 8; ++e) {
        int k = 8 * g + e;
        float wvv = (k < 27) ? wgt[nf * 27 + k] : 0.0f;
        wf[e] = f2bf(wvv);
    }
    // ---- bias for acc init: D row m = oc = g*4 + reg
    float bi[4];
    #pragma unroll
    for (int r = 0; r < 4; ++r) bi[r] = bias[g * 4 + r];

    // ---- per-lane invariant tap offsets (elements). Tap t = c*9+ky*3+kx.
    // k>=27 clamps to t=26 (finite smem value; A-side pad is exact 0).
    int inv[8];
    #pragma unroll
    for (int e = 0; e < 8; ++e) {
        int t  = min(8 * g + e, 26);
        int c  = (t >= 18) + (t >= 9);
        int t9 = t - 9 * c;
        int rr = (t9 * 22) >> 6;         // t9/3 for t9 in [0,8]
        int s  = t9 - 3 * rr;
        inv[e] = (c * SMH_ + 4 * wv + rr) * SMW_ + nf + s;
    }

    // ---- 16 sets: (row 0..3) x (sx 0..3); one 16x16x32 MFMA each ----
    #pragma unroll
    for (int row = 0; row < 4; ++row) {
        #pragma unroll
        for (int sx = 0; sx < 4; ++sx) {
            const int off = row * SMW_ + sx * 16;   // folds into ds_read offset:
            bf16x8 tf;
            #pragma unroll
            for (int e = 0; e < 8; ++e)
                tf[e] = f2bf(smem[inv[e] + off]);

            f32x4 acc = {bi[0], bi[1], bi[2], bi[3]};
            acc = __builtin_amdgcn_mfma_f32_16x16x32_bf16(wf, tf, acc, 0, 0, 0);

            // channel-min: 4 in-lane regs, then across the 4 k-groups
            float m = fminf(fminf(acc[0], acc[1]), fminf(acc[2], acc[3]));
            m = fminf(m, __shfl_xor(m, 16));
            m = fminf(m, __shfl_xor(m, 32));

            float t = fast_tanh(fast_tanh(m));

            if (lane < 16) {
                int ox = ox0 + sx * 16 + lane;
                int oy = oy0 + 4 * wv + row;
                if (ox < OW_ && oy < OH_)
                    out[((size_t)b * OH_ + oy) * OW_ + ox] = t;
            }
        }
    }
}

extern "C" void kernel_launch(void* const* d_in, const int* in_sizes, int n_in,
                              void* d_out, int out_size, void* d_ws, size_t ws_size,
                              hipStream_t stream) {
    const float* x    = (const float*)d_in[0];
    const float* wgt  = (const float*)d_in[1];
    const float* bias = (const float*)d_in[2];
    float* out = (float*)d_out;

    dim3 grid(B_ * TILES_X_ * TILES_Y_);   // 16384 blocks
    conv3x3_min_tanh_mfma<<<grid, 256, 0, stream>>>(x, wgt, bias, out);
}

// Round 7
// 109.125 us; speedup vs baseline: 4.4218x; 1.1079x over previous
//
#include <hip/hip_runtime.h>
#include <hip/hip_bf16.h>
#include <stdint.h>

// Problem constants
#define B_  64
#define C_  3
#define H_  512
#define W_  512
#define OC_ 16
#define OH_ 510
#define OW_ 510

// Tile: 256-thread block -> 64(x) x 16(y) outputs. 4 waves; wave w owns
// y-rows 4w..4w+3. Per wave: 16 MFMA sets (4 rows x 4 x-subtiles of 16).
#define TX_ 64
#define TY_ 16
#define TILES_X_ 8    // ceil(510/64)
#define TILES_Y_ 32   // ceil(510/16)
#define SMW_ 66       // TX+2
#define SMH_ 18       // TY+2

typedef __attribute__((ext_vector_type(8))) short bf16x8;   // MFMA A/B frag
typedef __attribute__((ext_vector_type(4))) float f32x4;    // MFMA C/D frag

// NaN-safe tanh: 1 - 2/(e^{2x}+1). e=inf -> 1 (no inf/inf NaN).
__device__ __forceinline__ float fast_tanh(float v) {
    float e = __expf(2.0f * v);
    return 1.0f - 2.0f * __builtin_amdgcn_rcpf(e + 1.0f);
}
__device__ __forceinline__ uint16_t f2bf_u16(float f) {
    __hip_bfloat16 h = __float2bfloat16(f);   // RNE
    return *reinterpret_cast<uint16_t*>(&h);
}

__global__ __launch_bounds__(256, 4)
void conv3x3_min_tanh_mfma(const float* __restrict__ x,
                           const float* __restrict__ wgt,
                           const float* __restrict__ bias,
                           float* __restrict__ out) {
    // bf16 tile: 3*18*66*2 = 14256 B
    __shared__ uint16_t smem[C_ * SMH_ * SMW_];

    const int blk = blockIdx.x;
    const int bx = blk % TILES_X_;
    const int by = (blk / TILES_X_) % TILES_Y_;
    const int b  = blk / (TILES_X_ * TILES_Y_);
    const int ox0 = bx * TX_;
    const int oy0 = by * TY_;

    // ---- stage input tile as bf16 (border-clamped; clamps feed dead pixels)
    const float* xb = x + (size_t)b * C_ * H_ * W_;
    constexpr int NSTAGE = C_ * SMH_ * SMW_;   // 3564
    for (int i = threadIdx.x; i < NSTAGE; i += 256) {
        int c   = i / (SMH_ * SMW_);
        int rem = i - c * (SMH_ * SMW_);
        int r   = rem / SMW_;
        int xx  = rem - r * SMW_;
        int gy  = min(oy0 + r,  H_ - 1);
        int gx  = min(ox0 + xx, W_ - 1);
        smem[i] = f2bf_u16(xb[(c * H_ + gy) * W_ + gx]);
    }
    __syncthreads();

    const int lane = threadIdx.x & 63;
    const int wv   = threadIdx.x >> 6;   // wave id 0..3
    const int nf   = lane & 15;          // A: oc ; B: pixel-x offset
    const int g    = lane >> 4;          // k-chunk: k = 8g+e

    // ---- W-frag (A): A[m=nf][k=8g+e] = wgt[nf*27+k], 0-pad k>=27 ----
    bf16x8 wf;
    #pragma unroll
    for (int e = 0; e < 8; ++e) {
        int k = 8 * g + e;
        float wvv = (k < 27) ? wgt[nf * 27 + k] : 0.0f;
        wf[e] = (short)f2bf_u16(wvv);
    }
    // ---- bias: D row m = g*4 + reg ----
    float bi[4];
    #pragma unroll
    for (int r = 0; r < 4; ++r) bi[r] = bias[g * 4 + r];

    // ---- per-lane invariant tap offsets (u16 elements). Tap t = c*9+ky*3+kx.
    // k>=27 clamps to t=26 (valid memory; A-side pad is exact 0).
    int inv[8];
    #pragma unroll
    for (int e = 0; e < 8; ++e) {
        int t  = min(8 * g + e, 26);
        int c  = (t >= 18) + (t >= 9);
        int t9 = t - 9 * c;
        int rr = (t9 * 22) >> 6;         // t9/3 for t9 in [0,8]
        int s  = t9 - 3 * rr;
        inv[e] = (c * SMH_ + 4 * wv + rr) * SMW_ + nf + s;
    }

    // ---- 4 rows x 4 sx; one 16x16x32 MFMA per set; batched row epilogue ----
    #pragma unroll
    for (int row = 0; row < 4; ++row) {
        float mrow[4];
        #pragma unroll
        for (int sx = 0; sx < 4; ++sx) {
            const int off = row * SMW_ + sx * 16;   // compile-time per set
            uint32_t tr[4];
            #pragma unroll
            for (int j = 0; j < 4; ++j) {
                uint32_t lo = smem[inv[2 * j]     + off];  // ds_read_u16, folded offset
                uint32_t hi = smem[inv[2 * j + 1] + off];
                tr[j] = lo | (hi << 16);                   // v_lshl_or_b32
            }
            bf16x8 tf = __builtin_bit_cast(bf16x8, tr);

            f32x4 acc = {bi[0], bi[1], bi[2], bi[3]};
            acc = __builtin_amdgcn_mfma_f32_16x16x32_bf16(wf, tf, acc, 0, 0, 0);

            // channel-min: 4 in-lane rows, then across the 4 k-groups
            float m = fminf(fminf(acc[0], acc[1]), fminf(acc[2], acc[3]));
            m = fminf(m, __shfl_xor(m, 16));
            m = fminf(m, __shfl_xor(m, 32));
            mrow[sx] = m;   // every lane now holds min for pixel col = lane&15
        }

        // one tanh + one fully-coalesced 64-wide store per row
        const int sel = lane >> 4;
        float mm = mrow[0];
        mm = (sel == 1) ? mrow[1] : mm;
        mm = (sel == 2) ? mrow[2] : mm;
        mm = (sel == 3) ? mrow[3] : mm;
        float t = fast_tanh(fast_tanh(mm));

        int oy = oy0 + 4 * wv + row;
        int ox = ox0 + lane;
        if (oy < OH_ && ox < OW_)
            out[((size_t)b * OH_ + oy) * OW_ + ox] = t;
    }
}

extern "C" void kernel_launch(void* const* d_in, const int* in_sizes, int n_in,
                              void* d_out, int out_size, void* d_ws, size_t ws_size,
                              hipStream_t stream) {
    const float* x    = (const float*)d_in[0];
    const float* wgt  = (const float*)d_in[1];
    const float* bias = (const float*)d_in[2];
    float* out = (float*)d_out;

    dim3 grid(B_ * TILES_X_ * TILES_Y_);   // 16384 blocks
    conv3x3_min_tanh_mfma<<<grid, 256, 0, stream>>>(x, wgt, bias, out);
}

// Round 9
// 98.666 us; speedup vs baseline: 4.8905x; 1.1060x over previous
//
#include <hip/hip_runtime.h>
#include <hip/hip_bf16.h>
#include <stdint.h>

// Problem constants
#define B_  64
#define C_  3
#define H_  512
#define W_  512
#define OC_ 16
#define OH_ 510
#define OW_ 510

// Tile geometry: 256-thread block -> 64(x) x 16(y) outputs; wave wv owns rows
// 4wv..4wv+3; per wave 16 MFMA sets (4 rows x 4 sx), 2 MFMAs per set (K=36).
#define TX_ 64
#define TY_ 16
#define TILES_X_ 8    // ceil(510/64)
#define TILES_Y_ 32   // ceil(510/16)
#define SMH_ 18       // value rows per channel (TY+2)
#define PXW_ 68       // u32 pair slots per row (x=0..67; reads reach x=65)

typedef __attribute__((ext_vector_type(8))) short bf16x8;   // MFMA A/B frag
typedef __attribute__((ext_vector_type(4))) float f32x4;    // MFMA C/D frag

// NaN-safe tanh: 1 - 2/(e^{2x}+1); e=inf -> 1 (no inf/inf NaN).
__device__ __forceinline__ float fast_tanh(float v) {
    float e = __expf(2.0f * v);
    return 1.0f - 2.0f * __builtin_amdgcn_rcpf(e + 1.0f);
}
__device__ __forceinline__ uint16_t bf16u(float f) {
    __hip_bfloat16 h = __float2bfloat16(f);   // RNE
    return __builtin_bit_cast(uint16_t, h);
}
__device__ __forceinline__ uint32_t pack2bf(float v0, float v1) {
    return (uint32_t)bf16u(v0) | ((uint32_t)bf16u(v1) << 16);
}

// k-permutation: 18 u32 pairs, pair p: c=p/6, pc=p%6, ky=pc>>1, xs=(pc&1)*2.
// Pair covers kx = xs+h (h=0,1); kx==3 slots get weight 0 (x-overhang).
// Pairs 0..15 -> MFMA1; pairs 16,17 (c2,ky2) -> MFMA2 (rest of K zero).

// ---- prep kernel: bake A-fragments + bias vectors into ws (3 KB) ----
// ws layout (bytes): [0)  wf1 u16[64][8]   (1024)
//                    [1024) wf2 u16[64][8] (1024)
//                    [2048) bias f32[64][4](1024)
__global__ void conv_prep(const float* __restrict__ wgt,
                          const float* __restrict__ bias,
                          uint16_t* __restrict__ ws16) {
    const int lane = threadIdx.x;        // 0..63
    const int nf = lane & 15, g = lane >> 4;
    #pragma unroll
    for (int e = 0; e < 8; ++e) {
        // MFMA1: k = 8g+e -> pair p = 4g + e/2, half h = e&1
        int p  = 4 * g + (e >> 1);
        int c  = (p >= 6) + (p >= 12);
        int pc = p - 6 * c;
        int ky = pc >> 1;
        int kx = ((pc & 1) << 1) + (e & 1);
        float w = (kx < 3) ? wgt[nf * 27 + c * 9 + ky * 3 + kx] : 0.0f;
        ws16[lane * 8 + e] = bf16u(w);
        // MFMA2: pair p2 = 16 + 4g + e/2, real only for p2<=17 (g==0, e<4)
        float w2 = 0.0f;
        int p2 = 16 + 4 * g + (e >> 1);
        if (p2 <= 17) {
            int pc2 = p2 - 12;               // 4 or 5 -> ky=2
            int kx2 = ((pc2 & 1) << 1) + (e & 1);
            if (kx2 < 3) w2 = wgt[nf * 27 + 2 * 9 + 2 * 3 + kx2];
        }
        ws16[512 + lane * 8 + e] = bf16u(w2);
    }
    float* bv = (float*)(ws16 + 1024);       // byte offset 2048
    #pragma unroll
    for (int r = 0; r < 4; ++r) bv[lane * 4 + r] = bias[g * 4 + r];
}

__global__ __launch_bounds__(256)
void conv3x3_min_tanh_mfma(const float* __restrict__ x,
                           const uint4* __restrict__ wsv,
                           float* __restrict__ out) {
    __shared__ uint32_t px[C_ * SMH_ * PXW_];   // 3672 u32 = 14688 B

    const int blk = blockIdx.x;
    const int bx = blk % TILES_X_;
    const int by = (blk / TILES_X_) % TILES_Y_;
    const int b  = blk / (TILES_X_ * TILES_Y_);
    const int ox0 = bx * TX_;
    const int oy0 = by * TY_;

    const int tid  = threadIdx.x;
    const int lane = tid & 63;
    const int wv   = tid >> 6;
    const int nf   = lane & 15;
    const int g    = lane >> 4;

    const float* xb = x + (size_t)b * (C_ * H_ * W_);

    // ---- staging: PX[c][r][x] = bf16(v[x]) | bf16(v[x+1])<<16 ----
    {
        const int gx0 = ox0 + lane;                 // <= 511 always
        const int gx1 = min(gx0 + 1, W_ - 1);       // clamps only bx=7,lane=63
        #pragma unroll
        for (int c = 0; c < C_; ++c) {
            for (int r = wv; r < SMH_; r += 4) {    // wave-uniform rows
                int gy = min(oy0 + r, H_ - 1);
                const float* xrow = xb + (c * H_ + gy) * W_;
                float v0 = xrow[gx0];
                float v1 = xrow[gx1];
                px[(c * SMH_ + r) * PXW_ + lane] = pack2bf(v0, v1);
            }
        }
        // extras: x in {64,65}; 3ch*18r*2 = 108 single-shot items
        if (tid < C_ * SMH_ * 2) {
            int c   = (tid >= 36) + (tid >= 72);
            int rem = tid - 36 * c;
            int r   = rem >> 1;
            int xx  = 64 + (rem & 1);
            int gy  = min(oy0 + r, H_ - 1);
            const float* xrow = xb + (c * H_ + gy) * W_;
            float v0 = xrow[min(ox0 + xx,     W_ - 1)];
            float v1 = xrow[min(ox0 + xx + 1, W_ - 1)];
            px[(c * SMH_ + r) * PXW_ + xx] = pack2bf(v0, v1);
        }
    }

    // ---- baked fragments (coalesced dwordx4; L2/L3-hot, 3 KB total) ----
    bf16x8 wf1 = __builtin_bit_cast(bf16x8, wsv[lane]);
    bf16x8 wf2 = __builtin_bit_cast(bf16x8, wsv[64 + lane]);
    f32x4  bi  = __builtin_bit_cast(f32x4,  wsv[128 + lane]);

    // ---- per-lane invariant pair indices (u32 elements) ----
    int inv1[4];
    #pragma unroll
    for (int j = 0; j < 4; ++j) {
        int p  = 4 * g + j;
        int c  = (p >= 6) + (p >= 12);
        int pc = p - 6 * c;
        int ky = pc >> 1;
        int xs = (pc & 1) << 1;
        inv1[j] = (c * SMH_ + 4 * wv + ky) * PXW_ + nf + xs;
    }
    int inv2[2];
    #pragma unroll
    for (int j = 0; j < 2; ++j) {
        int p  = min(16 + 4 * g + j, 17);   // g>0 lanes: harmless addr, A=0
        int xs = ((p - 12) & 1) << 1;
        inv2[j] = (2 * SMH_ + 4 * wv + 2) * PXW_ + nf + xs;
    }
    const int baddr = (lane ^ 32) << 2;     // hoisted ds_bpermute address

    __syncthreads();

    // ---- compute: 4 rows x 4 sx; 2 MFMAs per set; lane-local min ----
    const size_t orow0 = ((size_t)b * OH_ + (oy0 + 4 * wv)) * OW_ + ox0;
    const int oxl = ox0 + lane;

    #pragma unroll
    for (int row = 0; row < 4; ++row) {
        float mrow[4];
        #pragma unroll
        for (int sx = 0; sx < 4; ++sx) {
            const int off = row * PXW_ + sx * 16;   // folds into ds offset:
            uint32_t r0 = px[inv1[0] + off];
            uint32_t r1 = px[inv1[1] + off];
            uint32_t r2 = px[inv1[2] + off];
            uint32_t r3 = px[inv1[3] + off];
            bf16x8 tf1 = __builtin_bit_cast(bf16x8, uint4{r0, r1, r2, r3});
            uint32_t s0 = px[inv2[0] + off];
            uint32_t s1 = px[inv2[1] + off];
            bf16x8 tf2 = __builtin_bit_cast(bf16x8, uint4{s0, s1, 0u, 0u});

            f32x4 acc = bi;
            acc = __builtin_amdgcn_mfma_f32_16x16x32_bf16(wf1, tf1, acc, 0, 0, 0);
            acc = __builtin_amdgcn_mfma_f32_16x16x32_bf16(wf2, tf2, acc, 0, 0, 0);

            // min over oc: 4 in-lane regs, then xor16 (swizzle), xor32 (bpermute)
            float m = fminf(fminf(acc[0], acc[1]), fminf(acc[2], acc[3]));
            int sw = __builtin_amdgcn_ds_swizzle(__builtin_bit_cast(int, m), 0x401F);
            m = fminf(m, __builtin_bit_cast(float, sw));
            int bp = __builtin_amdgcn_ds_bpermute(baddr, __builtin_bit_cast(int, m));
            m = fminf(m, __builtin_bit_cast(float, bp));
            mrow[sx] = m;
        }
        // lane's own sx = g
        float mm = mrow[0];
        mm = (g == 1) ? mrow[1] : mm;
        mm = (g == 2) ? mrow[2] : mm;
        mm = (g == 3) ? mrow[3] : mm;
        float t = fast_tanh(fast_tanh(mm));

        int oy = oy0 + 4 * wv + row;
        if (oy < OH_ && oxl < OW_)
            out[orow0 + (size_t)row * OW_ + lane] = t;
    }
}

extern "C" void kernel_launch(void* const* d_in, const int* in_sizes, int n_in,
                              void* d_out, int out_size, void* d_ws, size_t ws_size,
                              hipStream_t stream) {
    const float* x    = (const float*)d_in[0];
    const float* wgt  = (const float*)d_in[1];
    const float* bias = (const float*)d_in[2];
    float* out = (float*)d_out;

    conv_prep<<<1, 64, 0, stream>>>(wgt, bias, (uint16_t*)d_ws);
    conv3x3_min_tanh_mfma<<<dim3(B_ * TILES_X_ * TILES_Y_), 256, 0, stream>>>(
        x, (const uint4*)d_ws, out);
}